// Round 16
// baseline (160.896 us; speedup 1.0000x reference)
//
#include <hip/hip_runtime.h>

#define B_ 8
#define T_ 1024
#define CG_ 256
#define CAPB 22
#define SENTE 0xFC01u        // pslot=31, j=1025

// ---------------- pack: x (8,1024,1024) f32 -> tok rows (B*Cg, T) u8 ----------------
__global__ __launch_bounds__(256) void pack_kernel(const float* __restrict__ x,
                                                   unsigned char* __restrict__ tok){
  __shared__ unsigned char tl[256][80];
  const int b  = blockIdx.x >> 4;
  const int t0 = (blockIdx.x & 15) << 6;
  const int g  = threadIdx.x;
  const float* xb = x + ((size_t)(b*T_ + t0) * 1024) + g*4;
  for (int tt = 0; tt < 64; tt++){
    const float4 v = *reinterpret_cast<const float4*>(xb + (size_t)tt*1024);
    unsigned int t = (v.x>0.f?1u:0u) | (v.y>0.f?2u:0u) | (v.z>0.f?4u:0u) | (v.w>0.f?8u:0u);
    tl[g][tt] = (unsigned char)t;
  }
  __syncthreads();
  const int gg  = threadIdx.x >> 2;
  const int off = (threadIdx.x & 3) * 16;
  for (int it = 0; it < 4; it++){
    const int g2 = gg + it*64;
    const uint4 w = *reinterpret_cast<const uint4*>(&tl[g2][off]);
    *reinterpret_cast<uint4*>(tok + (size_t)(b*CG_ + g2)*T_ + t0 + off) = w;
  }
}

// Bigram-sparse ROSA DP with REGISTER FORWARDING (no val[] array).
//   Bucket entry for j: (pslot<<11)|j where pslot = rank of j-1 in ITS bucket
//   (31 if invalid/overflow); ver byte = x[j-2] (31 if j<2 or pred overflow).
//   Step i: cand = bpermute(prun_prev, pslot); trig = (ver == x[i-2])
//     <=> j-1 was in bucket(i-1) at slot pslot => rn = cand+1 (exact), else rn=2.
//   run-1 keys precomputed (pvk); deferred argmax via 3-DPP group maxes + M8.
//   All LDS traffic is conflict-free (sequential reads, bpermute, fixed writes).
struct alignas(16) RowLds {
  unsigned short bg[256*CAPB];   // 11264 B: entries; sentinel 0xFC01
  unsigned char  bgv[256*CAPB];  // 5632 B: ver bytes; build alias first 1024B = cnt u32[256]
  unsigned char  t[1040];        // tokens + pad
  unsigned int   M8[320];        // [64][5] cols 0..2; build alias first 1024B = rk u8[1024]
  unsigned int   trash[64];
};                               // 19472 B/wave, x4 = 77888 B -> 2 blocks/CU

__global__ __launch_bounds__(256, 2) void rosa_fw_kernel(const unsigned char* __restrict__ tok,
                                                         unsigned char* __restrict__ pred){
  __shared__ RowLds S[4];
  const int wave = threadIdx.x >> 6;
  const unsigned int lane = threadIdx.x & 63u;
  const int row = blockIdx.x * 4 + wave;
  RowLds& R = S[wave];

  // stage tokens + pad
  { const uint4 v = *reinterpret_cast<const uint4*>(tok + (size_t)row*T_ + lane*16);
    *reinterpret_cast<uint4*>(&R.t[lane*16]) = v;
    if (lane == 0u) *reinterpret_cast<uint4*>(&R.t[1024]) = make_uint4(0,0,0,0); }
  // zero cnt (bgv alias, first 1024B); rk (M8 alias, first 1024B) = 31
  { *reinterpret_cast<uint4*>((char*)R.bgv + lane*16) = make_uint4(0,0,0,0);
    const unsigned int f = 0x1F1F1F1Fu;
    *reinterpret_cast<uint4*>((char*)R.M8 + lane*16) = make_uint4(f,f,f,f); }

  // tokens -> registers
  unsigned int vtokk[16];
  #pragma unroll
  for (int k = 0; k < 16; k++) vtokk[k] = R.t[k*64 + lane];

  unsigned int* const cntp = reinterpret_cast<unsigned int*>(R.bgv);
  unsigned char* const rkp = reinterpret_cast<unsigned char*>(R.M8);

  // pass1: ranks (order irrelevant)
  #pragma unroll
  for (int k = 0; k < 16; k++){
    const unsigned int j = (unsigned)k*64u + lane;
    if (j >= 1u){
      const unsigned int v2 = ((unsigned)R.t[j-1] << 4) | (unsigned)R.t[j];
      const unsigned int r = atomicAdd(&cntp[v2], 1u);
      rkp[j] = (unsigned char)(r < 31u ? r : 31u);
    }
  }
  // sentinel fills (overwrites cnt alias; rk stays intact in M8)
  { const unsigned int se = SENTE | (SENTE << 16);
    const uint4 s4 = make_uint4(se,se,se,se);
    uint4* p = reinterpret_cast<uint4*>(R.bg);          // 11264/16 = 704
    #pragma unroll
    for (int m = 0; m < 11; m++) p[m*64 + lane] = s4;
    const unsigned int f = 0x1F1F1F1Fu;
    const uint4 f4 = make_uint4(f,f,f,f);
    uint4* q = reinterpret_cast<uint4*>(R.bgv);         // 5632/16 = 352
    #pragma unroll
    for (int m = 0; m < 6; m++){ const int idx = m*64 + (int)lane; if (idx < 352) q[idx] = f4; }
  }
  // pass2: packed entries + ver bytes
  #pragma unroll
  for (int k = 0; k < 16; k++){
    const unsigned int j = (unsigned)k*64u + lane;
    if (j >= 1u){
      const unsigned int v2 = ((unsigned)R.t[j-1] << 4) | (unsigned)R.t[j];
      const unsigned int rj = rkp[j];
      const unsigned int rm = rkp[j-1];                 // rk[0] = 31 (init) for j=1
      if (rj < (unsigned)CAPB){
        const unsigned int entry = (rm << 11) | j;
        const unsigned int ver = (j >= 2u && rm < (unsigned)CAPB) ? (unsigned)R.t[j-2] : 31u;
        R.bg [v2*CAPB + rj] = (unsigned short)entry;
        R.bgv[v2*CAPB + rj] = (unsigned char)ver;
      }
    }
  }

  // ---- build prevocc run-1 keys (pvk) ----
  const unsigned long long below = (1ull << lane) - 1ull;
  unsigned int pvk[16];
  { int lp1c = -1;
    #pragma unroll 1
    for (int c = 0; c < 16; c++){
      const unsigned int tj = vtokk[c];
      const unsigned long long b0 = __ballot((tj & 1u) != 0u);
      const unsigned long long b1 = __ballot((tj & 2u) != 0u);
      const unsigned long long b2 = __ballot((tj & 4u) != 0u);
      const unsigned long long b3 = __ballot((tj & 8u) != 0u);
      unsigned long long mm = ((tj & 1u) ? b0 : ~b0) & ((tj & 2u) ? b1 : ~b1)
                            & ((tj & 4u) ? b2 : ~b2) & ((tj & 8u) ? b3 : ~b3);
      const unsigned long long mlo = mm & below;
      const int pin = 63 - __builtin_clzll(mlo | 1ull);
      const int pg  = __builtin_amdgcn_ds_bpermute((int)(tj << 2), lp1c);
      const int pv  = mlo ? (c*64 + pin) : pg;
      pvk[c] = (pv < 0) ? 0u : (1024u + (unsigned)pv);
      unsigned long long mv = ((lane & 1u) ? b0 : ~b0) & ((lane & 2u) ? b1 : ~b1)
                            & ((lane & 4u) ? b2 : ~b2) & ((lane & 8u) ? b3 : ~b3);
      if (mv) lp1c = c*64 + 63 - __builtin_clzll(mv);
    } }

  // ---- main loop setup ----
  const bool lane22 = (lane < (unsigned)CAPB);
  const bool realw  = ((lane & 7u) == 7u) && (lane < 24u);  // lanes 7/15/23 -> cols 0..2
  unsigned int* const wbase0 = realw ? &R.M8[lane >> 3] : &R.trash[lane];
  const unsigned int wstep = realw ? 5u : 0u;

  int s_xi  = __builtin_amdgcn_readlane((int)vtokk[0], 0);
  int s_xp1 = __builtin_amdgcn_readlane((int)vtokk[0], 1);
  int s_xm1 = 30, s_xm2 = 30;                 // x[i-1], x[i-2]; 30 = never-match
  unsigned int enA, enB, evA, evB;
  { const unsigned int bn0 = ((unsigned)s_xi) * (CAPB*2u);               // (0<<4)|x0
    enA = *(const unsigned short*)((const char*)R.bg + bn0 + lane*2u);
    evA = *((const unsigned char*)R.bgv + (bn0 >> 1) + lane);
    const unsigned int bn1 = ((((unsigned)s_xi) << 4) | (unsigned)s_xp1) * (CAPB*2u);
    enB = *(const unsigned short*)((const char*)R.bg + bn1 + lane*2u);
    evB = *((const unsigned char*)R.bgv + (bn1 >> 1) + lane); }
  int prun = 0;

#define RSTEP(I_, NEXTTOK_EXPR) do {                                              \
    const int i_ = (I_);                                                          \
    const unsigned int en = lane22 ? enA : SENTE;                                 \
    const unsigned int psl4 = (en >> 9) & 0x7Cu;                                  \
    const int cand = __builtin_amdgcn_ds_bpermute((int)psl4, prun);               \
    const unsigned int jl = en & 0x7FFu;                                          \
    const int s_xp2 = (NEXTTOK_EXPR);                                             \
    const unsigned int s_bb = ((((unsigned)s_xp1) << 4) | (unsigned)s_xp2) * (CAPB*2u); \
    const unsigned int enN = *(const unsigned short*)((const char*)R.bg + s_bb + lane*2u); \
    const unsigned int evN = *((const unsigned char*)R.bgv + (s_bb >> 1) + lane); \
    const unsigned int rn = (evA == (unsigned int)s_xm2) ? ((unsigned)cand + 1u) : 2u; \
    unsigned int key = (rn << 10) | jl;                                           \
    key = (jl < (unsigned int)i_) ? key : 0u;                                     \
    int bb = (int)key, tt;                                                        \
    tt = __builtin_amdgcn_mov_dpp(bb, 0x111, 0xf, 0xf, true); bb = ((unsigned)tt > (unsigned)bb) ? tt : bb; \
    tt = __builtin_amdgcn_mov_dpp(bb, 0x112, 0xf, 0xf, true); bb = ((unsigned)tt > (unsigned)bb) ? tt : bb; \
    tt = __builtin_amdgcn_mov_dpp(bb, 0x114, 0xf, 0xf, true); bb = ((unsigned)tt > (unsigned)bb) ? tt : bb; \
    *wptr = (unsigned int)bb; wptr += wstep;                                      \
    prun = (int)rn;                                                               \
    enA = enB; enB = enN; evA = evB; evB = evN;                                   \
    s_xm2 = s_xm1; s_xm1 = s_xi; s_xi = s_xp1; s_xp1 = s_xp2;                     \
  } while(0)

  #pragma unroll
  for (int i0 = 0; i0 < 16; i0++){
    unsigned int* wptr = wbase0;
    #pragma unroll 2
    for (int di = 0; di < 62; di++){
      RSTEP(i0*64 + di, __builtin_amdgcn_readlane((int)vtokk[i0], di + 2));
    }
    RSTEP(i0*64 + 62, __builtin_amdgcn_readlane((int)vtokk[(i0+1) & 15], (i0 < 15) ? 0 : 62));
    RSTEP(i0*64 + 63, __builtin_amdgcn_readlane((int)vtokk[(i0+1) & 15], (i0 < 15) ? 1 : 63));
    // block epilogue: lane s reduces M8[s][0..2] + precomputed run-1 key
    const unsigned int b5 = lane * 5u;
    unsigned int ab = R.M8[b5];
    { const unsigned int v1 = R.M8[b5 + 1u]; ab = v1 > ab ? v1 : ab; }
    { const unsigned int v2 = R.M8[b5 + 2u]; ab = v2 > ab ? v2 : ab; }
    { const unsigned int v3 = pvk[i0];       ab = v3 > ab ? v3 : ab; }
    unsigned int pidx = (ab & 1023u) + 1u;
    pidx = pidx > 1023u ? 1023u : pidx;
    const unsigned int pt = R.t[pidx];
    pred[(size_t)row*T_ + i0*64 + lane] = (unsigned char)((ab >= 1024u) ? pt : 0u);
  }
#undef RSTEP
}

// ---------------- expand: pred (B*Cg, T) u8 -> out (B,T,C) f32 ----------------
__global__ __launch_bounds__(256) void expand_kernel(const unsigned char* __restrict__ pred,
                                                     const float* __restrict__ emb0,
                                                     const float* __restrict__ emb1,
                                                     float* __restrict__ out){
  __shared__ unsigned char pl[64][80];
  const int bid = blockIdx.x;
  const int g0 = (bid & 3) << 6;
  const int t0 = ((bid >> 2) & 15) << 6;
  const int b  = bid >> 6;
  const int k  = threadIdx.x;
  {
    const int gg = k >> 2, off = (k & 3) * 16;
    const uint4 v = *reinterpret_cast<const uint4*>(pred + (size_t)(b*CG_ + g0 + gg)*T_ + t0 + off);
    *reinterpret_cast<uint4*>(&pl[gg][off]) = v;
  }
  __syncthreads();
  const int gg = k & 63;
  const int w  = k >> 6;
  const float4 e0 = *reinterpret_cast<const float4*>(emb0 + (g0+gg)*4);
  const float4 e1 = *reinterpret_cast<const float4*>(emb1 + (g0+gg)*4);
  for (int it = 0; it < 16; it++){
    const int tt = it*4 + w;
    const unsigned int pb = pl[gg][tt];
    float4 o;
    o.x = (pb & 1u) ? e1.x : e0.x;
    o.y = (pb & 2u) ? e1.y : e0.y;
    o.z = (pb & 4u) ? e1.z : e0.z;
    o.w = (pb & 8u) ? e1.w : e0.w;
    *reinterpret_cast<float4*>(out + (size_t)(b*T_ + t0 + tt)*1024 + (g0+gg)*4) = o;
  }
}

extern "C" void kernel_launch(void* const* d_in, const int* in_sizes, int n_in,
                              void* d_out, int out_size, void* d_ws, size_t ws_size,
                              hipStream_t stream){
  const float* x    = (const float*)d_in[0];
  const float* emb0 = (const float*)d_in[1];
  const float* emb1 = (const float*)d_in[2];
  float* out = (float*)d_out;
  unsigned char* tok  = (unsigned char*)d_ws;
  unsigned char* pred = tok + (size_t)B_*CG_*T_;
  pack_kernel<<<128, 256, 0, stream>>>(x, tok);
  rosa_fw_kernel<<<(B_*CG_)/4, 256, 0, stream>>>(tok, pred);
  expand_kernel<<<512, 256, 0, stream>>>(pred, emb0, emb1, out);
}

// Round 17
// 129.985 us; speedup vs baseline: 1.2378x; 1.2378x over previous
//
#include <hip/hip_runtime.h>

#define B_ 8
#define T_ 1024
#define CG_ 256
#define CAPB 22
#define SENTE 0xFC01u        // pslot=31, j=1025

// ---------------- pack: x (8,1024,1024) f32 -> tok rows (B*Cg, T) u8 ----------------
__global__ __launch_bounds__(256) void pack_kernel(const float* __restrict__ x,
                                                   unsigned char* __restrict__ tok){
  __shared__ unsigned char tl[256][80];
  const int b  = blockIdx.x >> 4;
  const int t0 = (blockIdx.x & 15) << 6;
  const int g  = threadIdx.x;
  const float* xb = x + ((size_t)(b*T_ + t0) * 1024) + g*4;
  for (int tt = 0; tt < 64; tt++){
    const float4 v = *reinterpret_cast<const float4*>(xb + (size_t)tt*1024);
    unsigned int t = (v.x>0.f?1u:0u) | (v.y>0.f?2u:0u) | (v.z>0.f?4u:0u) | (v.w>0.f?8u:0u);
    tl[g][tt] = (unsigned char)t;
  }
  __syncthreads();
  const int gg  = threadIdx.x >> 2;
  const int off = (threadIdx.x & 3) * 16;
  for (int it = 0; it < 4; it++){
    const int g2 = gg + it*64;
    const uint4 w = *reinterpret_cast<const uint4*>(&tl[g2][off]);
    *reinterpret_cast<uint4*>(tok + (size_t)(b*CG_ + g2)*T_ + t0 + off) = w;
  }
}

// Bigram-sparse ROSA DP, register forwarding, TWO STEPS PER ITERATION:
//   step 2m in lanes 0-31, step 2m+1 in lanes 32-63 (entries in ll=0..21 each).
//   fwd register: lanes 0-21 = (run(j,2m)<<11)|j by slot; lanes 32-53 = step 2m+1;
//   other lanes sentinel (2<<11)|1025.
//   bp1: step-2m lanes fetch pred (step 2m-1) from lanes 32+pslot of fwd;
//   bp2: step-2m+1 lanes fetch from lanes pslot of the freshly packed lower half.
//   Verify by position: fetched_j == j-1  =>  rn = fetched_run+1, else rn = 2
//   (exact: each position lives in exactly one bucket; stale => prev run was 1).
//   Shared per-iteration: 1 bucket read (per-half bucket), 1 key/mask, 1 3-DPP
//   reduce (row_shr stays in 16-lane rows), 1 M8 write (upper cols offset +5).
//   Step-0 bucket primed EMPTY so step 1 sees all-sentinel => rn=2 (exact).
struct alignas(16) RowLds {
  unsigned short bg[256*CAPB];   // 11264 B: entries (pslot<<11)|j, sentinel 0xFC01
                                 // build alias first 1024 B = cnt u32[256]
  unsigned char  t[1040];        // tokens + pad
  unsigned int   M8[320];        // [64][5] cols 0..2; build alias first 1024 B = rk u8[1024]
  unsigned int   trash[64];
};                               // 13840 B/wave, x4 = 55360 B -> 2 blocks/CU

__global__ __launch_bounds__(256, 2) void rosa_fw2_kernel(const unsigned char* __restrict__ tok,
                                                          unsigned char* __restrict__ pred){
  __shared__ RowLds S[4];
  const int wave = threadIdx.x >> 6;
  const unsigned int lane = threadIdx.x & 63u;
  const int row = blockIdx.x * 4 + wave;
  RowLds& R = S[wave];

  // stage tokens + pad
  { const uint4 v = *reinterpret_cast<const uint4*>(tok + (size_t)row*T_ + lane*16);
    *reinterpret_cast<uint4*>(&R.t[lane*16]) = v;
    if (lane == 0u) *reinterpret_cast<uint4*>(&R.t[1024]) = make_uint4(0,0,0,0); }
  // zero cnt (bg alias, first 1024B); rk (M8 alias, first 1024B) = 31
  { *reinterpret_cast<uint4*>((char*)R.bg + lane*16) = make_uint4(0,0,0,0);
    const unsigned int f = 0x1F1F1F1Fu;
    *reinterpret_cast<uint4*>((char*)R.M8 + lane*16) = make_uint4(f,f,f,f); }

  // tokens -> registers
  unsigned int vtokk[16];
  #pragma unroll
  for (int k = 0; k < 16; k++) vtokk[k] = R.t[k*64 + lane];

  unsigned int* const cntp = reinterpret_cast<unsigned int*>(R.bg);
  unsigned char* const rkp = reinterpret_cast<unsigned char*>(R.M8);

  // pass1: ranks (insertion order irrelevant)
  #pragma unroll
  for (int k = 0; k < 16; k++){
    const unsigned int j = (unsigned)k*64u + lane;
    if (j >= 1u){
      const unsigned int v2 = ((unsigned)R.t[j-1] << 4) | (unsigned)R.t[j];
      const unsigned int r = atomicAdd(&cntp[v2], 1u);
      rkp[j] = (unsigned char)(r < 31u ? r : 31u);
    }
  }
  // sentinel-fill bg (overwrites cnt alias; rk in M8 stays intact)
  { const unsigned int se = SENTE | (SENTE << 16);
    const uint4 s4 = make_uint4(se,se,se,se);
    uint4* p = reinterpret_cast<uint4*>(R.bg);          // 11264/16 = 704 = 11*64
    #pragma unroll
    for (int m = 0; m < 11; m++) p[m*64 + lane] = s4; }
  // pass2: packed entries
  #pragma unroll
  for (int k = 0; k < 16; k++){
    const unsigned int j = (unsigned)k*64u + lane;
    if (j >= 1u){
      const unsigned int v2 = ((unsigned)R.t[j-1] << 4) | (unsigned)R.t[j];
      const unsigned int rj = rkp[j];
      const unsigned int rm = rkp[j-1];                 // rk[0]=31 init for j=1
      if (rj < (unsigned)CAPB)
        R.bg[v2*CAPB + rj] = (unsigned short)((rm << 11) | j);
    }
  }

  // ---- build prevocc run-1 keys (pvk) ----
  const unsigned long long below = (1ull << lane) - 1ull;
  unsigned int pvk[16];
  { int lp1c = -1;
    #pragma unroll 1
    for (int c = 0; c < 16; c++){
      const unsigned int tj = vtokk[c];
      const unsigned long long b0 = __ballot((tj & 1u) != 0u);
      const unsigned long long b1 = __ballot((tj & 2u) != 0u);
      const unsigned long long b2 = __ballot((tj & 4u) != 0u);
      const unsigned long long b3 = __ballot((tj & 8u) != 0u);
      unsigned long long mm = ((tj & 1u) ? b0 : ~b0) & ((tj & 2u) ? b1 : ~b1)
                            & ((tj & 4u) ? b2 : ~b2) & ((tj & 8u) ? b3 : ~b3);
      const unsigned long long mlo = mm & below;
      const int pin = 63 - __builtin_clzll(mlo | 1ull);
      const int pg  = __builtin_amdgcn_ds_bpermute((int)(tj << 2), lp1c);
      const int pv  = mlo ? (c*64 + pin) : pg;
      pvk[c] = (pv < 0) ? 0u : (1024u + (unsigned)pv);
      unsigned long long mv = ((lane & 1u) ? b0 : ~b0) & ((lane & 2u) ? b1 : ~b1)
                            & ((lane & 4u) ? b2 : ~b2) & ((lane & 8u) ? b3 : ~b3);
      if (mv) lp1c = c*64 + 63 - __builtin_clzll(mv);
    } }

  // ---- main loop setup ----
  const unsigned int llq = lane & 31u;
  const bool hbb   = (lane >= 32u);
  const bool lane22 = (llq < (unsigned)CAPB);
  const bool realw = ((llq & 7u) == 7u) && (llq < 24u);   // llq 7/15/23
  unsigned int* const wbase0 = realw ? &R.M8[(llq >> 3) + (hbb ? 5u : 0u)] : &R.trash[lane];
  const unsigned int wstep = realw ? 10u : 0u;
  const unsigned int ll2 = llq * 2u;

  const int x0 = __builtin_amdgcn_readlane((int)vtokk[0], 0);
  const int x1 = __builtin_amdgcn_readlane((int)vtokk[0], 1);
  // prime: step 0 bucket EMPTY (sentinel); step 1 bucket = bigram(x0,x1)
  unsigned int enA;
  { const unsigned int bn1 = (((unsigned)x0 << 4) | (unsigned)x1) * (CAPB*2u);
    const unsigned int e1 = *(const unsigned short*)((const char*)R.bg + bn1 + ll2);
    enA = hbb ? e1 : SENTE; }
  unsigned int fwd = (2u << 11) | 1025u;
  unsigned int ilane = hbb ? 1u : 0u;           // step index per half; +=2 per iter
  int s_xc = x1;                                // x[2m+1]

#define RSTEP2(T2_, T3_) do {                                                     \
    const unsigned int en = lane22 ? enA : SENTE;                                 \
    const unsigned int psl4 = (en >> 9) & 0x7Cu;                                  \
    const int bp1 = __builtin_amdgcn_ds_bpermute((int)(psl4 | 128u), (int)fwd);   \
    const unsigned int jl = en & 0x7FFu;                                          \
    const unsigned int jlm1 = jl - 1u;                                            \
    const int t2 = (T2_); const int t3 = (T3_);                                   \
    const unsigned int bnlo = ((((unsigned)s_xc) << 4) | (unsigned)t2) * (CAPB*2u); \
    const unsigned int bnhi = ((((unsigned)t2) << 4) | (unsigned)t3) * (CAPB*2u); \
    const unsigned int bnv = hbb ? bnhi : bnlo;                                   \
    const unsigned int enN = *(const unsigned short*)((const char*)R.bg + bnv + ll2); \
    const unsigned int rn_lo = (((unsigned)bp1 & 0x7FFu) == jlm1) ? (((unsigned)bp1 >> 11) + 1u) : 2u; \
    const unsigned int fwd_tmp = (rn_lo << 11) | jl;                              \
    const int bp2 = __builtin_amdgcn_ds_bpermute((int)psl4, (int)fwd_tmp);        \
    const unsigned int rn_hi = (((unsigned)bp2 & 0x7FFu) == jlm1) ? (((unsigned)bp2 >> 11) + 1u) : 2u; \
    fwd = hbb ? ((rn_hi << 11) | jl) : fwd_tmp;                                   \
    const unsigned int rn = hbb ? rn_hi : rn_lo;                                  \
    unsigned int key = (rn << 10) | jl;                                           \
    key = (jl < ilane) ? key : 0u;                                                \
    int bb = (int)key, tt;                                                        \
    tt = __builtin_amdgcn_mov_dpp(bb, 0x111, 0xf, 0xf, true); bb = ((unsigned)tt > (unsigned)bb) ? tt : bb; \
    tt = __builtin_amdgcn_mov_dpp(bb, 0x112, 0xf, 0xf, true); bb = ((unsigned)tt > (unsigned)bb) ? tt : bb; \
    tt = __builtin_amdgcn_mov_dpp(bb, 0x114, 0xf, 0xf, true); bb = ((unsigned)tt > (unsigned)bb) ? tt : bb; \
    *wptr = (unsigned int)bb; wptr += wstep;                                      \
    ilane += 2u;                                                                  \
    enA = enN; s_xc = t3;                                                         \
  } while(0)

  #pragma unroll
  for (int i0 = 0; i0 < 16; i0++){
    unsigned int* wptr = wbase0;
    #pragma unroll 2
    for (int m = 0; m < 31; m++){
      RSTEP2(__builtin_amdgcn_readlane((int)vtokk[i0], 2*m + 2),
             __builtin_amdgcn_readlane((int)vtokk[i0], 2*m + 3));
    }
    // peeled m=31: tokens 64,65 come from the next chunk (clamped at the end)
    { const int nc = (i0 < 15) ? (i0 + 1) : 15;
      RSTEP2(__builtin_amdgcn_readlane((int)vtokk[nc], (i0 < 15) ? 0 : 62),
             __builtin_amdgcn_readlane((int)vtokk[nc], (i0 < 15) ? 1 : 63)); }
    // block epilogue: lane s reduces M8[s][0..2] + precomputed run-1 key
    const unsigned int b5 = lane * 5u;
    unsigned int ab = R.M8[b5];
    { const unsigned int v1 = R.M8[b5 + 1u]; ab = v1 > ab ? v1 : ab; }
    { const unsigned int v2 = R.M8[b5 + 2u]; ab = v2 > ab ? v2 : ab; }
    { const unsigned int v3 = pvk[i0];       ab = v3 > ab ? v3 : ab; }
    unsigned int pidx = (ab & 1023u) + 1u;
    pidx = pidx > 1023u ? 1023u : pidx;
    const unsigned int pt = R.t[pidx];
    pred[(size_t)row*T_ + i0*64 + lane] = (unsigned char)((ab >= 1024u) ? pt : 0u);
  }
#undef RSTEP2
}

// ---------------- expand: pred (B*Cg, T) u8 -> out (B,T,C) f32 ----------------
__global__ __launch_bounds__(256) void expand_kernel(const unsigned char* __restrict__ pred,
                                                     const float* __restrict__ emb0,
                                                     const float* __restrict__ emb1,
                                                     float* __restrict__ out){
  __shared__ unsigned char pl[64][80];
  const int bid = blockIdx.x;
  const int g0 = (bid & 3) << 6;
  const int t0 = ((bid >> 2) & 15) << 6;
  const int b  = bid >> 6;
  const int k  = threadIdx.x;
  {
    const int gg = k >> 2, off = (k & 3) * 16;
    const uint4 v = *reinterpret_cast<const uint4*>(pred + (size_t)(b*CG_ + g0 + gg)*T_ + t0 + off);
    *reinterpret_cast<uint4*>(&pl[gg][off]) = v;
  }
  __syncthreads();
  const int gg = k & 63;
  const int w  = k >> 6;
  const float4 e0 = *reinterpret_cast<const float4*>(emb0 + (g0+gg)*4);
  const float4 e1 = *reinterpret_cast<const float4*>(emb1 + (g0+gg)*4);
  for (int it = 0; it < 16; it++){
    const int tt = it*4 + w;
    const unsigned int pb = pl[gg][tt];
    float4 o;
    o.x = (pb & 1u) ? e1.x : e0.x;
    o.y = (pb & 2u) ? e1.y : e0.y;
    o.z = (pb & 4u) ? e1.z : e0.z;
    o.w = (pb & 8u) ? e1.w : e0.w;
    *reinterpret_cast<float4*>(out + (size_t)(b*T_ + t0 + tt)*1024 + (g0+gg)*4) = o;
  }
}

extern "C" void kernel_launch(void* const* d_in, const int* in_sizes, int n_in,
                              void* d_out, int out_size, void* d_ws, size_t ws_size,
                              hipStream_t stream){
  const float* x    = (const float*)d_in[0];
  const float* emb0 = (const float*)d_in[1];
  const float* emb1 = (const float*)d_in[2];
  float* out = (float*)d_out;
  unsigned char* tok  = (unsigned char*)d_ws;
  unsigned char* pred = tok + (size_t)B_*CG_*T_;
  pack_kernel<<<128, 256, 0, stream>>>(x, tok);
  rosa_fw2_kernel<<<(B_*CG_)/4, 256, 0, stream>>>(tok, pred);
  expand_kernel<<<512, 256, 0, stream>>>(pred, emb0, emb1, out);
}

// Round 18
// 119.544 us; speedup vs baseline: 1.3459x; 1.0873x over previous
//
#include <hip/hip_runtime.h>

#define B_ 8
#define T_ 1024
#define CG_ 256
#define CAPB 22
#define SENTE 0xFC01u        // pslot2=31, j=1025

// ---------------- pack: x (8,1024,1024) f32 -> tok rows (B*Cg, T) u8 ----------------
__global__ __launch_bounds__(256) void pack_kernel(const float* __restrict__ x,
                                                   unsigned char* __restrict__ tok){
  __shared__ unsigned char tl[256][80];
  const int b  = blockIdx.x >> 4;
  const int t0 = (blockIdx.x & 15) << 6;
  const int g  = threadIdx.x;
  const float* xb = x + ((size_t)(b*T_ + t0) * 1024) + g*4;
  for (int tt = 0; tt < 64; tt++){
    const float4 v = *reinterpret_cast<const float4*>(xb + (size_t)tt*1024);
    unsigned int t = (v.x>0.f?1u:0u) | (v.y>0.f?2u:0u) | (v.z>0.f?4u:0u) | (v.w>0.f?8u:0u);
    tl[g][tt] = (unsigned char)t;
  }
  __syncthreads();
  const int gg  = threadIdx.x >> 2;
  const int off = (threadIdx.x & 3) * 16;
  for (int it = 0; it < 4; it++){
    const int g2 = gg + it*64;
    const uint4 w = *reinterpret_cast<const uint4*>(&tl[g2][off]);
    *reinterpret_cast<uint4*>(tok + (size_t)(b*CG_ + g2)*T_ + t0 + off) = w;
  }
}

// Bigram-sparse ROSA DP, DISTANCE-2 register forwarding, 2 steps/iteration:
//   step 2m in lanes 0-31, step 2m+1 in lanes 32-63 (entries at ll=0..21).
//   Bucket entry: (pslot2<<11)|j where pslot2 = rank of j-2 in ITS bucket (31 inval);
//   ver byte = x[j-2] (31 if j<2).
//   ONE bpermute/iteration from the PREVIOUS iteration's fwd (same half =
//   distance 2): rn = (fetched_j==j-2) ? fetched_run+2 : (ver==x[i-2] ? 3 : 2).
//   Exact: run(j,i) = 2 + lcs(j-2,i-2); pos-identity gives lcs>=2 case, ver the =1.
//   Shared per-iteration: 1 bucket u16 + 1 ver u8 read, 1 key/mask, 1 3-DPP
//   reduce (row_shr stays in 16-lane rows), 1 M8 write. Step-0 bucket primed
//   EMPTY; s_a=s_b=30 make steps 0/1 ver-fail -> rn=2 (exact).
struct alignas(16) RowLds {
  unsigned short bg[256*CAPB];   // 11264 B; build alias first 1024 B = cnt u32[256]
  unsigned char  bgv[256*CAPB];  // 5632 B ver bytes
  unsigned char  t[1040];        // tokens + pad
  unsigned int   M8[320];        // [64][5] cols 0..2; build alias first 1024 B = rk u8[1024]
  unsigned int   trash[64];
};                               // 19472 B/wave, x4 = 77888 B -> 2 blocks/CU

__global__ __launch_bounds__(256, 2) void rosa_fw3_kernel(const unsigned char* __restrict__ tok,
                                                          unsigned char* __restrict__ pred){
  __shared__ RowLds S[4];
  const int wave = threadIdx.x >> 6;
  const unsigned int lane = threadIdx.x & 63u;
  const int row = blockIdx.x * 4 + wave;
  RowLds& R = S[wave];

  // stage tokens + pad
  { const uint4 v = *reinterpret_cast<const uint4*>(tok + (size_t)row*T_ + lane*16);
    *reinterpret_cast<uint4*>(&R.t[lane*16]) = v;
    if (lane == 0u) *reinterpret_cast<uint4*>(&R.t[1024]) = make_uint4(0,0,0,0); }
  // zero cnt (bg alias); rk (M8 alias) = 31
  { *reinterpret_cast<uint4*>((char*)R.bg + lane*16) = make_uint4(0,0,0,0);
    const unsigned int f = 0x1F1F1F1Fu;
    *reinterpret_cast<uint4*>((char*)R.M8 + lane*16) = make_uint4(f,f,f,f); }

  // tokens -> registers
  unsigned int vtokk[16];
  #pragma unroll
  for (int k = 0; k < 16; k++) vtokk[k] = R.t[k*64 + lane];

  unsigned int* const cntp = reinterpret_cast<unsigned int*>(R.bg);
  unsigned char* const rkp = reinterpret_cast<unsigned char*>(R.M8);

  // pass1: ranks (insertion order irrelevant)
  #pragma unroll
  for (int k = 0; k < 16; k++){
    const unsigned int j = (unsigned)k*64u + lane;
    if (j >= 1u){
      const unsigned int v2 = ((unsigned)R.t[j-1] << 4) | (unsigned)R.t[j];
      const unsigned int r = atomicAdd(&cntp[v2], 1u);
      rkp[j] = (unsigned char)(r < 31u ? r : 31u);
    }
  }
  // sentinel fills (overwrite cnt alias; rk in M8 stays intact)
  { const unsigned int se = SENTE | (SENTE << 16);
    const uint4 s4 = make_uint4(se,se,se,se);
    uint4* p = reinterpret_cast<uint4*>(R.bg);          // 704 = 11*64
    #pragma unroll
    for (int m = 0; m < 11; m++) p[m*64 + lane] = s4;
    const unsigned int f = 0x1F1F1F1Fu;
    const uint4 f4 = make_uint4(f,f,f,f);
    uint4* q = reinterpret_cast<uint4*>(R.bgv);         // 352
    #pragma unroll
    for (int m = 0; m < 6; m++){ const int idx = m*64 + (int)lane; if (idx < 352) q[idx] = f4; } }
  // pass2: packed entries + ver bytes
  #pragma unroll
  for (int k = 0; k < 16; k++){
    const unsigned int j = (unsigned)k*64u + lane;
    if (j >= 1u){
      const unsigned int v2 = ((unsigned)R.t[j-1] << 4) | (unsigned)R.t[j];
      const unsigned int rj = rkp[j];
      if (rj < (unsigned)CAPB){
        const unsigned int p2 = (j >= 2u) ? (unsigned)rkp[j-2] : 31u;   // rk[0]=31 init
        const unsigned int ver = (j >= 2u) ? (unsigned)R.t[j-2] : 31u;
        R.bg [v2*CAPB + rj] = (unsigned short)((p2 << 11) | j);
        R.bgv[v2*CAPB + rj] = (unsigned char)ver;
      }
    }
  }

  // ---- build prevocc run-1 keys (pvk) ----
  const unsigned long long below = (1ull << lane) - 1ull;
  unsigned int pvk[16];
  { int lp1c = -1;
    #pragma unroll 1
    for (int c = 0; c < 16; c++){
      const unsigned int tj = vtokk[c];
      const unsigned long long b0 = __ballot((tj & 1u) != 0u);
      const unsigned long long b1 = __ballot((tj & 2u) != 0u);
      const unsigned long long b2 = __ballot((tj & 4u) != 0u);
      const unsigned long long b3 = __ballot((tj & 8u) != 0u);
      unsigned long long mm = ((tj & 1u) ? b0 : ~b0) & ((tj & 2u) ? b1 : ~b1)
                            & ((tj & 4u) ? b2 : ~b2) & ((tj & 8u) ? b3 : ~b3);
      const unsigned long long mlo = mm & below;
      const int pin = 63 - __builtin_clzll(mlo | 1ull);
      const int pg  = __builtin_amdgcn_ds_bpermute((int)(tj << 2), lp1c);
      const int pv  = mlo ? (c*64 + pin) : pg;
      pvk[c] = (pv < 0) ? 0u : (1024u + (unsigned)pv);
      unsigned long long mv = ((lane & 1u) ? b0 : ~b0) & ((lane & 2u) ? b1 : ~b1)
                            & ((lane & 4u) ? b2 : ~b2) & ((lane & 8u) ? b3 : ~b3);
      if (mv) lp1c = c*64 + 63 - __builtin_clzll(mv);
    } }

  // ---- main loop setup ----
  const unsigned int llq = lane & 31u;
  const bool hbb    = (lane >= 32u);
  const bool lane22 = (llq < (unsigned)CAPB);
  const bool realw  = ((llq & 7u) == 7u) && (llq < 24u);   // llq 7/15/23
  unsigned int* const wbase0 = realw ? &R.M8[(llq >> 3) + (hbb ? 5u : 0u)] : &R.trash[lane];
  const unsigned int wstep = realw ? 10u : 0u;
  const unsigned int ll2 = llq * 2u;
  const unsigned int hb128 = hbb ? 128u : 0u;

  const int x0 = __builtin_amdgcn_readlane((int)vtokk[0], 0);
  const int x1 = __builtin_amdgcn_readlane((int)vtokk[0], 1);
  // prime: step-0 bucket EMPTY; step-1 bucket = bigram(x0,x1)
  unsigned int enA, evA;
  { const unsigned int bn1 = (((unsigned)x0 << 4) | (unsigned)x1) * (CAPB*2u);
    const unsigned int e1 = *(const unsigned short*)((const char*)R.bg + bn1 + ll2);
    const unsigned int v1 = *((const unsigned char*)R.bgv + (bn1 >> 1) + llq);
    enA = hbb ? e1 : SENTE;
    evA = hbb ? v1 : 31u; }
  unsigned int fwd = (2u << 11) | 1025u;
  unsigned int ilane = hbb ? 1u : 0u;
  int s_a = 30, s_b = 30, s_c = x0, s_d = x1;   // x[2m-2], x[2m-1], x[2m], x[2m+1]

#define RSTEP2(T2_, T3_) do {                                                     \
    const unsigned int en = lane22 ? enA : SENTE;                                 \
    const unsigned int psl4 = ((en >> 9) & 0x7Cu) | hb128;                        \
    const int bp = __builtin_amdgcn_ds_bpermute((int)psl4, (int)fwd);             \
    const unsigned int jl = en & 0x7FFu;                                          \
    const int t2 = (T2_); const int t3 = (T3_);                                   \
    const unsigned int bnlo = ((((unsigned)s_d) << 4) | (unsigned)t2) * (CAPB*2u); \
    const unsigned int bnhi = ((((unsigned)t2) << 4) | (unsigned)t3) * (CAPB*2u); \
    const unsigned int bnv = hbb ? bnhi : bnlo;                                   \
    const unsigned int enN = *(const unsigned short*)((const char*)R.bg + bnv + ll2); \
    const unsigned int evN = *((const unsigned char*)R.bgv + (bnv >> 1) + llq);   \
    const int sver = hbb ? s_b : s_a;                                             \
    const unsigned int fj = (unsigned)bp & 0x7FFu;                                \
    const unsigned int frun = ((unsigned)bp >> 11);                               \
    const unsigned int rn23 = (evA == (unsigned)sver) ? 3u : 2u;                  \
    const unsigned int rn = (fj == jl - 2u) ? (frun + 2u) : rn23;                 \
    fwd = (rn << 11) | jl;                                                        \
    unsigned int key = (rn << 10) | jl;                                           \
    key = (jl < ilane) ? key : 0u;                                                \
    int bb = (int)key, tt;                                                        \
    tt = __builtin_amdgcn_mov_dpp(bb, 0x111, 0xf, 0xf, true); bb = ((unsigned)tt > (unsigned)bb) ? tt : bb; \
    tt = __builtin_amdgcn_mov_dpp(bb, 0x112, 0xf, 0xf, true); bb = ((unsigned)tt > (unsigned)bb) ? tt : bb; \
    tt = __builtin_amdgcn_mov_dpp(bb, 0x114, 0xf, 0xf, true); bb = ((unsigned)tt > (unsigned)bb) ? tt : bb; \
    *wptr = (unsigned int)bb; wptr += wstep;                                      \
    ilane += 2u;                                                                  \
    enA = enN; evA = evN;                                                         \
    s_a = s_c; s_b = s_d; s_c = t2; s_d = t3;                                     \
  } while(0)

  #pragma unroll
  for (int i0 = 0; i0 < 16; i0++){
    unsigned int* wptr = wbase0;
    #pragma unroll 2
    for (int m = 0; m < 31; m++){
      RSTEP2(__builtin_amdgcn_readlane((int)vtokk[i0], 2*m + 2),
             __builtin_amdgcn_readlane((int)vtokk[i0], 2*m + 3));
    }
    // peeled m=31: tokens 64,65 come from the next chunk (clamped at the end)
    { const int nc = (i0 < 15) ? (i0 + 1) : 15;
      RSTEP2(__builtin_amdgcn_readlane((int)vtokk[nc], (i0 < 15) ? 0 : 62),
             __builtin_amdgcn_readlane((int)vtokk[nc], (i0 < 15) ? 1 : 63)); }
    // block epilogue: lane s reduces M8[s][0..2] + precomputed run-1 key
    const unsigned int b5 = lane * 5u;
    unsigned int ab = R.M8[b5];
    { const unsigned int v1 = R.M8[b5 + 1u]; ab = v1 > ab ? v1 : ab; }
    { const unsigned int v2 = R.M8[b5 + 2u]; ab = v2 > ab ? v2 : ab; }
    { const unsigned int v3 = pvk[i0];       ab = v3 > ab ? v3 : ab; }
    unsigned int pidx = (ab & 1023u) + 1u;
    pidx = pidx > 1023u ? 1023u : pidx;
    const unsigned int pt = R.t[pidx];
    pred[(size_t)row*T_ + i0*64 + lane] = (unsigned char)((ab >= 1024u) ? pt : 0u);
  }
#undef RSTEP2
}

// ---------------- expand: pred (B*Cg, T) u8 -> out (B,T,C) f32 ----------------
__global__ __launch_bounds__(256) void expand_kernel(const unsigned char* __restrict__ pred,
                                                     const float* __restrict__ emb0,
                                                     const float* __restrict__ emb1,
                                                     float* __restrict__ out){
  __shared__ unsigned char pl[64][80];
  const int bid = blockIdx.x;
  const int g0 = (bid & 3) << 6;
  const int t0 = ((bid >> 2) & 15) << 6;
  const int b  = bid >> 6;
  const int k  = threadIdx.x;
  {
    const int gg = k >> 2, off = (k & 3) * 16;
    const uint4 v = *reinterpret_cast<const uint4*>(pred + (size_t)(b*CG_ + g0 + gg)*T_ + t0 + off);
    *reinterpret_cast<uint4*>(&pl[gg][off]) = v;
  }
  __syncthreads();
  const int gg = k & 63;
  const int w  = k >> 6;
  const float4 e0 = *reinterpret_cast<const float4*>(emb0 + (g0+gg)*4);
  const float4 e1 = *reinterpret_cast<const float4*>(emb1 + (g0+gg)*4);
  for (int it = 0; it < 16; it++){
    const int tt = it*4 + w;
    const unsigned int pb = pl[gg][tt];
    float4 o;
    o.x = (pb & 1u) ? e1.x : e0.x;
    o.y = (pb & 2u) ? e1.y : e0.y;
    o.z = (pb & 4u) ? e1.z : e0.z;
    o.w = (pb & 8u) ? e1.w : e0.w;
    *reinterpret_cast<float4*>(out + (size_t)(b*T_ + t0 + tt)*1024 + (g0+gg)*4) = o;
  }
}

extern "C" void kernel_launch(void* const* d_in, const int* in_sizes, int n_in,
                              void* d_out, int out_size, void* d_ws, size_t ws_size,
                              hipStream_t stream){
  const float* x    = (const float*)d_in[0];
  const float* emb0 = (const float*)d_in[1];
  const float* emb1 = (const float*)d_in[2];
  float* out = (float*)d_out;
  unsigned char* tok  = (unsigned char*)d_ws;
  unsigned char* pred = tok + (size_t)B_*CG_*T_;
  pack_kernel<<<128, 256, 0, stream>>>(x, tok);
  rosa_fw3_kernel<<<(B_*CG_)/4, 256, 0, stream>>>(tok, pred);
  expand_kernel<<<512, 256, 0, stream>>>(pred, emb0, emb1, out);
}

// Round 19
// 116.870 us; speedup vs baseline: 1.3767x; 1.0229x over previous
//
#include <hip/hip_runtime.h>

#define B_ 8
#define T_ 1024
#define CG_ 256
#define CAPB 22
#define SENTE 0xFC01u        // pslot2=31, j=1025

// Bigram-sparse ROSA DP, distance-2 register forwarding (R18) + FUSED token
// pack (x read directly; pack kernel and tok buffer eliminated).
struct alignas(16) RowLds {
  unsigned short bg[256*CAPB];   // 11264 B; build alias first 1024 B = cnt u32[256]
  unsigned char  bgv[256*CAPB];  // 5632 B ver bytes
  unsigned char  t[1040];        // tokens + pad
  unsigned int   M8[320];        // [64][5] cols 0..2; build alias first 1024 B = rk u8[1024]
  unsigned int   trash[64];
};                               // 19472 B/wave, x4 = 77888 B -> 2 blocks/CU

__global__ __launch_bounds__(256, 2) void rosa_fw4_kernel(const float* __restrict__ x,
                                                          unsigned char* __restrict__ pred){
  __shared__ RowLds S[4];
  const int wave = threadIdx.x >> 6;
  const unsigned int lane = threadIdx.x & 63u;
  const int row = blockIdx.x * 4 + wave;
  RowLds& R = S[wave];

  // ---- fused pack: thread k builds tokens for t=4k..4k+3, all 4 rows ----
  {
    const int b   = blockIdx.x >> 6;          // 8 b values
    const int cg0 = (blockIdx.x & 63) << 2;   // first channel-group of this block
    const int k   = threadIdx.x;
    const float* xb = x + ((size_t)(b*T_ + 4*k) * 1024) + cg0*4;
    unsigned int tw0 = 0u, tw1 = 0u, tw2 = 0u, tw3 = 0u;
    #pragma unroll
    for (int j = 0; j < 4; j++){
      const float4 f0 = *reinterpret_cast<const float4*>(xb + (size_t)j*1024 + 0);
      const float4 f1 = *reinterpret_cast<const float4*>(xb + (size_t)j*1024 + 4);
      const float4 f2 = *reinterpret_cast<const float4*>(xb + (size_t)j*1024 + 8);
      const float4 f3 = *reinterpret_cast<const float4*>(xb + (size_t)j*1024 + 12);
      const unsigned int t0 = (f0.x>0.f?1u:0u)|(f0.y>0.f?2u:0u)|(f0.z>0.f?4u:0u)|(f0.w>0.f?8u:0u);
      const unsigned int t1 = (f1.x>0.f?1u:0u)|(f1.y>0.f?2u:0u)|(f1.z>0.f?4u:0u)|(f1.w>0.f?8u:0u);
      const unsigned int t2 = (f2.x>0.f?1u:0u)|(f2.y>0.f?2u:0u)|(f2.z>0.f?4u:0u)|(f2.w>0.f?8u:0u);
      const unsigned int t3 = (f3.x>0.f?1u:0u)|(f3.y>0.f?2u:0u)|(f3.z>0.f?4u:0u)|(f3.w>0.f?8u:0u);
      tw0 |= t0 << (8*j); tw1 |= t1 << (8*j); tw2 |= t2 << (8*j); tw3 |= t3 << (8*j);
    }
    *reinterpret_cast<unsigned int*>(&S[0].t[4*k]) = tw0;
    *reinterpret_cast<unsigned int*>(&S[1].t[4*k]) = tw1;
    *reinterpret_cast<unsigned int*>(&S[2].t[4*k]) = tw2;
    *reinterpret_cast<unsigned int*>(&S[3].t[4*k]) = tw3;
    if (k < 4) *reinterpret_cast<uint4*>(&S[k].t[1024]) = make_uint4(0,0,0,0);
  }
  __syncthreads();

  // zero cnt (bg alias); rk (M8 alias) = 31
  { *reinterpret_cast<uint4*>((char*)R.bg + lane*16) = make_uint4(0,0,0,0);
    const unsigned int f = 0x1F1F1F1Fu;
    *reinterpret_cast<uint4*>((char*)R.M8 + lane*16) = make_uint4(f,f,f,f); }

  // tokens -> registers
  unsigned int vtokk[16];
  #pragma unroll
  for (int k = 0; k < 16; k++) vtokk[k] = R.t[k*64 + lane];

  unsigned int* const cntp = reinterpret_cast<unsigned int*>(R.bg);
  unsigned char* const rkp = reinterpret_cast<unsigned char*>(R.M8);

  // pass1: ranks (insertion order irrelevant)
  #pragma unroll
  for (int k = 0; k < 16; k++){
    const unsigned int j = (unsigned)k*64u + lane;
    if (j >= 1u){
      const unsigned int v2 = ((unsigned)R.t[j-1] << 4) | (unsigned)R.t[j];
      const unsigned int r = atomicAdd(&cntp[v2], 1u);
      rkp[j] = (unsigned char)(r < 31u ? r : 31u);
    }
  }
  // sentinel fills (overwrite cnt alias; rk in M8 stays intact)
  { const unsigned int se = SENTE | (SENTE << 16);
    const uint4 s4 = make_uint4(se,se,se,se);
    uint4* p = reinterpret_cast<uint4*>(R.bg);          // 704 = 11*64
    #pragma unroll
    for (int m = 0; m < 11; m++) p[m*64 + lane] = s4;
    const unsigned int f = 0x1F1F1F1Fu;
    const uint4 f4 = make_uint4(f,f,f,f);
    uint4* q = reinterpret_cast<uint4*>(R.bgv);         // 352
    #pragma unroll
    for (int m = 0; m < 6; m++){ const int idx = m*64 + (int)lane; if (idx < 352) q[idx] = f4; } }
  // pass2: packed entries + ver bytes
  #pragma unroll
  for (int k = 0; k < 16; k++){
    const unsigned int j = (unsigned)k*64u + lane;
    if (j >= 1u){
      const unsigned int v2 = ((unsigned)R.t[j-1] << 4) | (unsigned)R.t[j];
      const unsigned int rj = rkp[j];
      if (rj < (unsigned)CAPB){
        const unsigned int p2 = (j >= 2u) ? (unsigned)rkp[j-2] : 31u;   // rk[0]=31 init
        const unsigned int ver = (j >= 2u) ? (unsigned)R.t[j-2] : 31u;
        R.bg [v2*CAPB + rj] = (unsigned short)((p2 << 11) | j);
        R.bgv[v2*CAPB + rj] = (unsigned char)ver;
      }
    }
  }

  // ---- build prevocc run-1 keys (pvk) ----
  const unsigned long long below = (1ull << lane) - 1ull;
  unsigned int pvk[16];
  { int lp1c = -1;
    #pragma unroll 1
    for (int c = 0; c < 16; c++){
      const unsigned int tj = vtokk[c];
      const unsigned long long b0 = __ballot((tj & 1u) != 0u);
      const unsigned long long b1 = __ballot((tj & 2u) != 0u);
      const unsigned long long b2 = __ballot((tj & 4u) != 0u);
      const unsigned long long b3 = __ballot((tj & 8u) != 0u);
      unsigned long long mm = ((tj & 1u) ? b0 : ~b0) & ((tj & 2u) ? b1 : ~b1)
                            & ((tj & 4u) ? b2 : ~b2) & ((tj & 8u) ? b3 : ~b3);
      const unsigned long long mlo = mm & below;
      const int pin = 63 - __builtin_clzll(mlo | 1ull);
      const int pg  = __builtin_amdgcn_ds_bpermute((int)(tj << 2), lp1c);
      const int pv  = mlo ? (c*64 + pin) : pg;
      pvk[c] = (pv < 0) ? 0u : (1024u + (unsigned)pv);
      unsigned long long mv = ((lane & 1u) ? b0 : ~b0) & ((lane & 2u) ? b1 : ~b1)
                            & ((lane & 4u) ? b2 : ~b2) & ((lane & 8u) ? b3 : ~b3);
      if (mv) lp1c = c*64 + 63 - __builtin_clzll(mv);
    } }

  // ---- main loop setup ----
  const unsigned int llq = lane & 31u;
  const bool hbb    = (lane >= 32u);
  const bool lane22 = (llq < (unsigned)CAPB);
  const bool realw  = ((llq & 7u) == 7u) && (llq < 24u);   // llq 7/15/23
  unsigned int* const wbase0 = realw ? &R.M8[(llq >> 3) + (hbb ? 5u : 0u)] : &R.trash[lane];
  const unsigned int wstep = realw ? 10u : 0u;
  const unsigned int ll2 = llq * 2u;
  const unsigned int hb128 = hbb ? 128u : 0u;

  const int x0 = __builtin_amdgcn_readlane((int)vtokk[0], 0);
  const int x1 = __builtin_amdgcn_readlane((int)vtokk[0], 1);
  // prime: step-0 bucket EMPTY; step-1 bucket = bigram(x0,x1)
  unsigned int enA, evA;
  { const unsigned int bn1 = (((unsigned)x0 << 4) | (unsigned)x1) * (CAPB*2u);
    const unsigned int e1 = *(const unsigned short*)((const char*)R.bg + bn1 + ll2);
    const unsigned int v1 = *((const unsigned char*)R.bgv + (bn1 >> 1) + llq);
    enA = hbb ? e1 : SENTE;
    evA = hbb ? v1 : 31u; }
  unsigned int fwd = (2u << 11) | 1027u;        // sentinel: j+2 form
  unsigned int ilane = hbb ? 1u : 0u;
  int s_a = 30, s_b = 30, s_c = x0, s_d = x1;   // x[2m-2], x[2m-1], x[2m], x[2m+1]

#define RSTEP2(T2_, T3_) do {                                                     \
    const unsigned int en = lane22 ? enA : SENTE;                                 \
    const unsigned int psl4 = ((en >> 9) & 0x7Cu) | hb128;                        \
    const int bp = __builtin_amdgcn_ds_bpermute((int)psl4, (int)fwd);             \
    const unsigned int jl = en & 0x7FFu;                                          \
    const int t2 = (T2_); const int t3 = (T3_);                                   \
    const unsigned int bnlo = ((((unsigned)s_d) << 4) | (unsigned)t2) * (CAPB*2u); \
    const unsigned int bnhi = ((((unsigned)t2) << 4) | (unsigned)t3) * (CAPB*2u); \
    const unsigned int bnv = hbb ? bnhi : bnlo;                                   \
    const unsigned int enN = *(const unsigned short*)((const char*)R.bg + bnv + ll2); \
    const unsigned int evN = *((const unsigned char*)R.bgv + (bnv >> 1) + llq);   \
    const int sver = hbb ? s_b : s_a;                                             \
    const unsigned int fj = (unsigned)bp & 0x7FFu;                                \
    const unsigned int frun = ((unsigned)bp >> 11);                               \
    const unsigned int rn23 = (evA == (unsigned)sver) ? 3u : 2u;                  \
    const unsigned int rn = (fj == jl) ? (frun + 2u) : rn23;                      \
    fwd = (rn << 11) | (jl + 2u);                                                 \
    unsigned int key = (rn << 10) | jl;                                           \
    key = (jl < ilane) ? key : 0u;                                                \
    int bb = (int)key, tt;                                                        \
    tt = __builtin_amdgcn_mov_dpp(bb, 0x111, 0xf, 0xf, true); bb = ((unsigned)tt > (unsigned)bb) ? tt : bb; \
    tt = __builtin_amdgcn_mov_dpp(bb, 0x112, 0xf, 0xf, true); bb = ((unsigned)tt > (unsigned)bb) ? tt : bb; \
    tt = __builtin_amdgcn_mov_dpp(bb, 0x114, 0xf, 0xf, true); bb = ((unsigned)tt > (unsigned)bb) ? tt : bb; \
    *wptr = (unsigned int)bb; wptr += wstep;                                      \
    ilane += 2u;                                                                  \
    enA = enN; evA = evN;                                                         \
    s_a = s_c; s_b = s_d; s_c = t2; s_d = t3;                                     \
  } while(0)

  #pragma unroll
  for (int i0 = 0; i0 < 16; i0++){
    unsigned int* wptr = wbase0;
    #pragma unroll 2
    for (int m = 0; m < 31; m++){
      RSTEP2(__builtin_amdgcn_readlane((int)vtokk[i0], 2*m + 2),
             __builtin_amdgcn_readlane((int)vtokk[i0], 2*m + 3));
    }
    // peeled m=31: tokens 64,65 come from the next chunk (clamped at the end)
    { const int nc = (i0 < 15) ? (i0 + 1) : 15;
      RSTEP2(__builtin_amdgcn_readlane((int)vtokk[nc], (i0 < 15) ? 0 : 62),
             __builtin_amdgcn_readlane((int)vtokk[nc], (i0 < 15) ? 1 : 63)); }
    // block epilogue: lane s reduces M8[s][0..2] + precomputed run-1 key
    const unsigned int b5 = lane * 5u;
    unsigned int ab = R.M8[b5];
    { const unsigned int v1 = R.M8[b5 + 1u]; ab = v1 > ab ? v1 : ab; }
    { const unsigned int v2 = R.M8[b5 + 2u]; ab = v2 > ab ? v2 : ab; }
    { const unsigned int v3 = pvk[i0];       ab = v3 > ab ? v3 : ab; }
    unsigned int pidx = (ab & 1023u) + 1u;
    pidx = pidx > 1023u ? 1023u : pidx;
    const unsigned int pt = R.t[pidx];
    pred[(size_t)row*T_ + i0*64 + lane] = (unsigned char)((ab >= 1024u) ? pt : 0u);
  }
#undef RSTEP2
}

// ---------------- expand: pred (B*Cg, T) u8 -> out (B,T,C) f32 ----------------
__global__ __launch_bounds__(256) void expand_kernel(const unsigned char* __restrict__ pred,
                                                     const float* __restrict__ emb0,
                                                     const float* __restrict__ emb1,
                                                     float* __restrict__ out){
  __shared__ unsigned char pl[64][80];
  const int bid = blockIdx.x;
  const int g0 = (bid & 3) << 6;
  const int t0 = ((bid >> 2) & 15) << 6;
  const int b  = bid >> 6;
  const int k  = threadIdx.x;
  {
    const int gg = k >> 2, off = (k & 3) * 16;
    const uint4 v = *reinterpret_cast<const uint4*>(pred + (size_t)(b*CG_ + g0 + gg)*T_ + t0 + off);
    *reinterpret_cast<uint4*>(&pl[gg][off]) = v;
  }
  __syncthreads();
  const int gg = k & 63;
  const int w  = k >> 6;
  const float4 e0 = *reinterpret_cast<const float4*>(emb0 + (g0+gg)*4);
  const float4 e1 = *reinterpret_cast<const float4*>(emb1 + (g0+gg)*4);
  for (int it = 0; it < 16; it++){
    const int tt = it*4 + w;
    const unsigned int pb = pl[gg][tt];
    float4 o;
    o.x = (pb & 1u) ? e1.x : e0.x;
    o.y = (pb & 2u) ? e1.y : e0.y;
    o.z = (pb & 4u) ? e1.z : e0.z;
    o.w = (pb & 8u) ? e1.w : e0.w;
    *reinterpret_cast<float4*>(out + (size_t)(b*T_ + t0 + tt)*1024 + (g0+gg)*4) = o;
  }
}

extern "C" void kernel_launch(void* const* d_in, const int* in_sizes, int n_in,
                              void* d_out, int out_size, void* d_ws, size_t ws_size,
                              hipStream_t stream){
  const float* x    = (const float*)d_in[0];
  const float* emb0 = (const float*)d_in[1];
  const float* emb1 = (const float*)d_in[2];
  float* out = (float*)d_out;
  unsigned char* pred = (unsigned char*)d_ws;     // 2 MiB
  rosa_fw4_kernel<<<(B_*CG_)/4, 256, 0, stream>>>(x, pred);
  expand_kernel<<<512, 256, 0, stream>>>(pred, emb0, emb1, out);
}

// Round 20
// 92.964 us; speedup vs baseline: 1.7307x; 1.2571x over previous
//
#include <hip/hip_runtime.h>

#define B_ 8
#define T_ 1024
#define CG_ 256
#define CAPB 22
#define SENTE 0xFC01u        // pslot2=31, j=1025

// Single fused kernel: token pack (from x) + bigram-sparse ROSA DP with
// distance-2 register forwarding + embedding expand (writes out directly).
struct alignas(16) RowLds {
  unsigned short bg[256*CAPB];   // 11264 B; build alias first 1024 B = cnt u32[256]
  unsigned char  bgv[256*CAPB];  // 5632 B ver bytes
  unsigned char  t[1040];        // tokens + pad
  unsigned int   M8[320];        // [64][5] cols 0..2; build alias first 1024 B = rk u8[1024]
  unsigned int   trash[64];
};                               // 19472 B/wave, x4 = 77888 B (+pb 512) -> 2 blocks/CU

__global__ __launch_bounds__(256, 2) void rosa_fused_kernel(const float* __restrict__ x,
                                                            const float* __restrict__ emb0,
                                                            const float* __restrict__ emb1,
                                                            float* __restrict__ out){
  __shared__ RowLds S[4];
  __shared__ unsigned char pb[2][4][64];
  const int wave = threadIdx.x >> 6;
  const unsigned int lane = threadIdx.x & 63u;
  RowLds& R = S[wave];
  const int b   = blockIdx.x >> 6;            // batch
  const int cg0 = (blockIdx.x & 63) << 2;     // first channel-group of this block

  // ---- fused pack: thread k builds tokens for t=4k..4k+3, all 4 rows ----
  {
    const int k = threadIdx.x;
    const float* xb = x + ((size_t)(b*T_ + 4*k) * 1024) + cg0*4;
    unsigned int tw0 = 0u, tw1 = 0u, tw2 = 0u, tw3 = 0u;
    #pragma unroll
    for (int j = 0; j < 4; j++){
      const float4 f0 = *reinterpret_cast<const float4*>(xb + (size_t)j*1024 + 0);
      const float4 f1 = *reinterpret_cast<const float4*>(xb + (size_t)j*1024 + 4);
      const float4 f2 = *reinterpret_cast<const float4*>(xb + (size_t)j*1024 + 8);
      const float4 f3 = *reinterpret_cast<const float4*>(xb + (size_t)j*1024 + 12);
      const unsigned int t0 = (f0.x>0.f?1u:0u)|(f0.y>0.f?2u:0u)|(f0.z>0.f?4u:0u)|(f0.w>0.f?8u:0u);
      const unsigned int t1 = (f1.x>0.f?1u:0u)|(f1.y>0.f?2u:0u)|(f1.z>0.f?4u:0u)|(f1.w>0.f?8u:0u);
      const unsigned int t2 = (f2.x>0.f?1u:0u)|(f2.y>0.f?2u:0u)|(f2.z>0.f?4u:0u)|(f2.w>0.f?8u:0u);
      const unsigned int t3 = (f3.x>0.f?1u:0u)|(f3.y>0.f?2u:0u)|(f3.z>0.f?4u:0u)|(f3.w>0.f?8u:0u);
      tw0 |= t0 << (8*j); tw1 |= t1 << (8*j); tw2 |= t2 << (8*j); tw3 |= t3 << (8*j);
    }
    *reinterpret_cast<unsigned int*>(&S[0].t[4*k]) = tw0;
    *reinterpret_cast<unsigned int*>(&S[1].t[4*k]) = tw1;
    *reinterpret_cast<unsigned int*>(&S[2].t[4*k]) = tw2;
    *reinterpret_cast<unsigned int*>(&S[3].t[4*k]) = tw3;
    if (k < 4) *reinterpret_cast<uint4*>(&S[k].t[1024]) = make_uint4(0,0,0,0);
  }
  // per-thread expand constants (independent of LDS; load before sync)
  const int kk = threadIdx.x;
  const int xr = kk & 3;                       // row handled in expand
  const int xt = kk >> 2;                      // t_local handled in expand
  const float4 e0r = *reinterpret_cast<const float4*>(emb0 + (cg0 + xr)*4);
  const float4 e1r = *reinterpret_cast<const float4*>(emb1 + (cg0 + xr)*4);
  float* const outp = out + ((size_t)b*T_*1024) + (size_t)(cg0 + xr)*4 + (size_t)xt*1024;
  __syncthreads();

  // zero cnt (bg alias); rk (M8 alias) = 31
  { *reinterpret_cast<uint4*>((char*)R.bg + lane*16) = make_uint4(0,0,0,0);
    const unsigned int f = 0x1F1F1F1Fu;
    *reinterpret_cast<uint4*>((char*)R.M8 + lane*16) = make_uint4(f,f,f,f); }

  // tokens -> registers
  unsigned int vtokk[16];
  #pragma unroll
  for (int k = 0; k < 16; k++) vtokk[k] = R.t[k*64 + lane];

  unsigned int* const cntp = reinterpret_cast<unsigned int*>(R.bg);
  unsigned char* const rkp = reinterpret_cast<unsigned char*>(R.M8);

  // pass1: ranks (insertion order irrelevant)
  #pragma unroll
  for (int k = 0; k < 16; k++){
    const unsigned int j = (unsigned)k*64u + lane;
    if (j >= 1u){
      const unsigned int v2 = ((unsigned)R.t[j-1] << 4) | (unsigned)R.t[j];
      const unsigned int r = atomicAdd(&cntp[v2], 1u);
      rkp[j] = (unsigned char)(r < 31u ? r : 31u);
    }
  }
  // sentinel fills (overwrite cnt alias; rk in M8 stays intact)
  { const unsigned int se = SENTE | (SENTE << 16);
    const uint4 s4 = make_uint4(se,se,se,se);
    uint4* p = reinterpret_cast<uint4*>(R.bg);          // 704 = 11*64
    #pragma unroll
    for (int m = 0; m < 11; m++) p[m*64 + lane] = s4;
    const unsigned int f = 0x1F1F1F1Fu;
    const uint4 f4 = make_uint4(f,f,f,f);
    uint4* q = reinterpret_cast<uint4*>(R.bgv);         // 352
    #pragma unroll
    for (int m = 0; m < 6; m++){ const int idx = m*64 + (int)lane; if (idx < 352) q[idx] = f4; } }
  // pass2: packed entries + ver bytes
  #pragma unroll
  for (int k = 0; k < 16; k++){
    const unsigned int j = (unsigned)k*64u + lane;
    if (j >= 1u){
      const unsigned int v2 = ((unsigned)R.t[j-1] << 4) | (unsigned)R.t[j];
      const unsigned int rj = rkp[j];
      if (rj < (unsigned)CAPB){
        const unsigned int p2 = (j >= 2u) ? (unsigned)rkp[j-2] : 31u;   // rk[0]=31 init
        const unsigned int ver = (j >= 2u) ? (unsigned)R.t[j-2] : 31u;
        R.bg [v2*CAPB + rj] = (unsigned short)((p2 << 11) | j);
        R.bgv[v2*CAPB + rj] = (unsigned char)ver;
      }
    }
  }

  // ---- build prevocc run-1 keys (pvk) ----
  const unsigned long long below = (1ull << lane) - 1ull;
  unsigned int pvk[16];
  { int lp1c = -1;
    #pragma unroll 1
    for (int c = 0; c < 16; c++){
      const unsigned int tj = vtokk[c];
      const unsigned long long b0 = __ballot((tj & 1u) != 0u);
      const unsigned long long b1 = __ballot((tj & 2u) != 0u);
      const unsigned long long b2 = __ballot((tj & 4u) != 0u);
      const unsigned long long b3 = __ballot((tj & 8u) != 0u);
      unsigned long long mm = ((tj & 1u) ? b0 : ~b0) & ((tj & 2u) ? b1 : ~b1)
                            & ((tj & 4u) ? b2 : ~b2) & ((tj & 8u) ? b3 : ~b3);
      const unsigned long long mlo = mm & below;
      const int pin = 63 - __builtin_clzll(mlo | 1ull);
      const int pg  = __builtin_amdgcn_ds_bpermute((int)(tj << 2), lp1c);
      const int pv  = mlo ? (c*64 + pin) : pg;
      pvk[c] = (pv < 0) ? 0u : (1024u + (unsigned)pv);
      unsigned long long mv = ((lane & 1u) ? b0 : ~b0) & ((lane & 2u) ? b1 : ~b1)
                            & ((lane & 4u) ? b2 : ~b2) & ((lane & 8u) ? b3 : ~b3);
      if (mv) lp1c = c*64 + 63 - __builtin_clzll(mv);
    } }

  // ---- main loop setup ----
  const unsigned int llq = lane & 31u;
  const bool hbb    = (lane >= 32u);
  const bool lane22 = (llq < (unsigned)CAPB);
  const bool realw  = ((llq & 7u) == 7u) && (llq < 24u);   // llq 7/15/23
  unsigned int* const wbase0 = realw ? &R.M8[(llq >> 3) + (hbb ? 5u : 0u)] : &R.trash[lane];
  const unsigned int wstep = realw ? 10u : 0u;
  const unsigned int ll2 = llq * 2u;
  const unsigned int hb128 = hbb ? 128u : 0u;

  const int x0 = __builtin_amdgcn_readlane((int)vtokk[0], 0);
  const int x1 = __builtin_amdgcn_readlane((int)vtokk[0], 1);
  // prime: step-0 bucket EMPTY; step-1 bucket = bigram(x0,x1)
  unsigned int enA, evA;
  { const unsigned int bn1 = (((unsigned)x0 << 4) | (unsigned)x1) * (CAPB*2u);
    const unsigned int e1 = *(const unsigned short*)((const char*)R.bg + bn1 + ll2);
    const unsigned int v1 = *((const unsigned char*)R.bgv + (bn1 >> 1) + llq);
    enA = hbb ? e1 : SENTE;
    evA = hbb ? v1 : 31u; }
  unsigned int fwd = (2u << 11) | 1027u;        // sentinel: j+2 form
  unsigned int ilane = hbb ? 1u : 0u;
  int s_a = 30, s_b = 30, s_c = x0, s_d = x1;   // x[2m-2], x[2m-1], x[2m], x[2m+1]

#define RSTEP2(T2_, T3_) do {                                                     \
    const unsigned int en = lane22 ? enA : SENTE;                                 \
    const unsigned int psl4 = ((en >> 9) & 0x7Cu) | hb128;                        \
    const int bp = __builtin_amdgcn_ds_bpermute((int)psl4, (int)fwd);             \
    const unsigned int jl = en & 0x7FFu;                                          \
    const int t2 = (T2_); const int t3 = (T3_);                                   \
    const unsigned int bnlo = ((((unsigned)s_d) << 4) | (unsigned)t2) * (CAPB*2u); \
    const unsigned int bnhi = ((((unsigned)t2) << 4) | (unsigned)t3) * (CAPB*2u); \
    const unsigned int bnv = hbb ? bnhi : bnlo;                                   \
    const unsigned int enN = *(const unsigned short*)((const char*)R.bg + bnv + ll2); \
    const unsigned int evN = *((const unsigned char*)R.bgv + (bnv >> 1) + llq);   \
    const int sver = hbb ? s_b : s_a;                                             \
    const unsigned int fj = (unsigned)bp & 0x7FFu;                                \
    const unsigned int frun = ((unsigned)bp >> 11);                               \
    const unsigned int rn23 = (evA == (unsigned)sver) ? 3u : 2u;                  \
    const unsigned int rn = (fj == jl) ? (frun + 2u) : rn23;                      \
    fwd = (rn << 11) | (jl + 2u);                                                 \
    unsigned int key = (rn << 10) | jl;                                           \
    key = (jl < ilane) ? key : 0u;                                                \
    int bb = (int)key, tt;                                                        \
    tt = __builtin_amdgcn_mov_dpp(bb, 0x111, 0xf, 0xf, true); bb = ((unsigned)tt > (unsigned)bb) ? tt : bb; \
    tt = __builtin_amdgcn_mov_dpp(bb, 0x112, 0xf, 0xf, true); bb = ((unsigned)tt > (unsigned)bb) ? tt : bb; \
    tt = __builtin_amdgcn_mov_dpp(bb, 0x114, 0xf, 0xf, true); bb = ((unsigned)tt > (unsigned)bb) ? tt : bb; \
    *wptr = (unsigned int)bb; wptr += wstep;                                      \
    ilane += 2u;                                                                  \
    enA = enN; evA = evN;                                                         \
    s_a = s_c; s_b = s_d; s_c = t2; s_d = t3;                                     \
  } while(0)

  #pragma unroll
  for (int i0 = 0; i0 < 16; i0++){
    unsigned int* wptr = wbase0;
    #pragma unroll 2
    for (int m = 0; m < 31; m++){
      RSTEP2(__builtin_amdgcn_readlane((int)vtokk[i0], 2*m + 2),
             __builtin_amdgcn_readlane((int)vtokk[i0], 2*m + 3));
    }
    // peeled m=31: tokens 64,65 come from the next chunk (clamped at the end)
    { const int nc = (i0 < 15) ? (i0 + 1) : 15;
      RSTEP2(__builtin_amdgcn_readlane((int)vtokk[nc], (i0 < 15) ? 0 : 62),
             __builtin_amdgcn_readlane((int)vtokk[nc], (i0 < 15) ? 1 : 63)); }
    // block epilogue: lane s reduces M8[s][0..2] + precomputed run-1 key
    const unsigned int b5 = lane * 5u;
    unsigned int ab = R.M8[b5];
    { const unsigned int v1 = R.M8[b5 + 1u]; ab = v1 > ab ? v1 : ab; }
    { const unsigned int v2 = R.M8[b5 + 2u]; ab = v2 > ab ? v2 : ab; }
    { const unsigned int v3 = pvk[i0];       ab = v3 > ab ? v3 : ab; }
    unsigned int pidx = (ab & 1023u) + 1u;
    pidx = pidx > 1023u ? 1023u : pidx;
    const unsigned int pt = R.t[pidx];
    pb[i0 & 1][wave][lane] = (unsigned char)((ab >= 1024u) ? pt : 0u);
    __syncthreads();
    // fused expand: thread k -> row (k&3), t_local (k>>2); 4 threads = 64B line
    { const unsigned int pbyte = pb[i0 & 1][xr][xt];
      float4 o;
      o.x = (pbyte & 1u) ? e1r.x : e0r.x;
      o.y = (pbyte & 2u) ? e1r.y : e0r.y;
      o.z = (pbyte & 4u) ? e1r.z : e0r.z;
      o.w = (pbyte & 8u) ? e1r.w : e0r.w;
      *reinterpret_cast<float4*>(outp + (size_t)(i0*64)*1024) = o; }
  }
#undef RSTEP2
}

extern "C" void kernel_launch(void* const* d_in, const int* in_sizes, int n_in,
                              void* d_out, int out_size, void* d_ws, size_t ws_size,
                              hipStream_t stream){
  const float* x    = (const float*)d_in[0];
  const float* emb0 = (const float*)d_in[1];
  const float* emb1 = (const float*)d_in[2];
  float* out = (float*)d_out;
  rosa_fused_kernel<<<(B_*CG_)/4, 256, 0, stream>>>(x, emb0, emb1, out);
}